// Round 2
// baseline (527.145 us; speedup 1.0000x reference)
//
#include <hip/hip_runtime.h>
#include <math.h>

// ---------------------------------------------------------------------------
// Shapes: B=64, N=133, NFEAT=75, NHID=128
//   x:(64,133,75) adj:(64,133,133)
//   emb_w:(75,150) gc1_w:(150,256) gc2_w:(256,128) gc3_w:(128,75)
//   gc4_w:(75,1) fc1_w:(132,3) fin_w:(4,1)
// out: 64 floats
//
// Structure: adj is ~8% dense. Build CSR neighbor lists once, then each GCN
// stage is ONE kernel per (batch, 64-col chunk): tiled GEMM t=p@W into LDS,
// sparse y=relu(A@t+b) in LDS, neighbor max-pool, write p_out. Entries with
// 0<a<=1e-5 are kept for the SpMM (stored at list tail) but excluded from
// pooling, matching reference semantics exactly.
// ---------------------------------------------------------------------------

#define NNODE 133
#define NSTRIDE 136   // per-row list capacity (>=133)

// Build neighbor lists. front: a>1e-5 (pool+spmm); back: 0<a<=1e-5 (spmm only).
__global__ __launch_bounds__(128)
void prep_nbr(const float* __restrict__ adj, int* __restrict__ cnt,
              unsigned char* __restrict__ idx, float* __restrict__ val)
{
    const int i = blockIdx.x, b = blockIdx.y;
    __shared__ int c0, c1;
    if (threadIdx.x == 0) { c0 = 0; c1 = 0; }
    __syncthreads();
    const float* ar = adj + ((long)b * NNODE + i) * NNODE;
    const long base = ((long)b * NNODE + i) * NSTRIDE;
    for (int j = threadIdx.x; j < NNODE; j += 128) {
        float a = ar[j];
        if (a > 1e-5f) {
            int p = atomicAdd(&c0, 1);
            idx[base + p] = (unsigned char)j; val[base + p] = a;
        } else if (a > 0.0f) {
            int p = atomicAdd(&c1, 1);
            idx[base + (NSTRIDE - 1) - p] = (unsigned char)j;
            val[base + (NSTRIDE - 1) - p] = a;
        }
    }
    __syncthreads();
    if (threadIdx.x == 0) {
        cnt[(b * NNODE + i) * 2 + 0] = c0;
        cnt[(b * NNODE + i) * 2 + 1] = c1;
    }
}

// Generic tiled GEMM (used for the embedding layer): C = act(A@B + bias).
template<int RELU, int BIAS>
__global__ __launch_bounds__(256)
void gemm_tiled(const float* __restrict__ A, const float* __restrict__ B,
                const float* __restrict__ bias, float* __restrict__ C,
                int M, int K, int N)
{
    __shared__ float As[16][68];
    __shared__ float Bs[16][68];
    const int bn = blockIdx.x * 64, bm = blockIdx.y * 64;
    const int tid = threadIdx.x;
    const int tx = tid & 15, ty = tid >> 4;
    const int la_k = tid & 15, la_m = tid >> 4;
    const int lb_n = tid & 63, lb_k = tid >> 6;
    float acc[4][4] = {};
    for (int k0 = 0; k0 < K; k0 += 16) {
#pragma unroll
        for (int p = 0; p < 4; ++p) {
            int m = la_m + p * 16, gm = bm + m, gk = k0 + la_k;
            As[la_k][m] = (gm < M && gk < K) ? A[(long)gm * K + gk] : 0.0f;
        }
#pragma unroll
        for (int p = 0; p < 4; ++p) {
            int k = lb_k + p * 4, gk = k0 + k, gn = bn + lb_n;
            Bs[k][lb_n] = (gk < K && gn < N) ? B[(long)gk * N + gn] : 0.0f;
        }
        __syncthreads();
#pragma unroll
        for (int k = 0; k < 16; ++k) {
            float4 av = *reinterpret_cast<const float4*>(&As[k][ty * 4]);
            float4 bv = *reinterpret_cast<const float4*>(&Bs[k][tx * 4]);
            float a[4] = {av.x, av.y, av.z, av.w};
            float bb[4] = {bv.x, bv.y, bv.z, bv.w};
#pragma unroll
            for (int i = 0; i < 4; ++i)
#pragma unroll
                for (int j = 0; j < 4; ++j)
                    acc[i][j] = fmaf(a[i], bb[j], acc[i][j]);
        }
        __syncthreads();
    }
#pragma unroll
    for (int i = 0; i < 4; ++i) {
        int gm = bm + ty * 4 + i;
        if (gm >= M) continue;
#pragma unroll
        for (int j = 0; j < 4; ++j) {
            int gn = bn + tx * 4 + j;
            if (gn >= N) continue;
            float v = acc[i][j];
            if (BIAS) v += bias[gn];
            if (RELU) v = fmaxf(v, 0.0f);
            C[(long)gm * N + gn] = v;
        }
    }
}

// Fused GCN stage for one (batch, 64-col chunk):
//   tS = p_in[b] @ W[:, n0:n0+64]        (tiled GEMM, 133x64 in LDS)
//   yS = relu(A_sparse @ tS + bias)      (CSR, in LDS)
//   p_out = neighbor-max-pool(yS)
__global__ __launch_bounds__(256)
void fused_stage(const float* __restrict__ p_in, int K,
                 const float* __restrict__ W, int N,
                 const float* __restrict__ bias,
                 const int* __restrict__ nbr_cnt,
                 const unsigned char* __restrict__ nbr_idx,
                 const float* __restrict__ nbr_val,
                 float* __restrict__ p_out)
{
    const int b = blockIdx.y;
    const int n0 = blockIdx.x * 64;
    const int CN = min(64, N - n0);
    const int tid = threadIdx.x;

    __shared__ float As[16][68];
    __shared__ float Bs[16][68];
    __shared__ float tS[NNODE][66];
    __shared__ float yS[NNODE][66];

    const int tx = tid & 15, ty = tid >> 4;
    const int la_k = tid & 15, la_m = tid >> 4;
    const int lb_n = tid & 63, lb_k = tid >> 6;
    const float* Ab = p_in + (long)b * NNODE * K;

    // ---- phase 1: tS = p_in[b] @ W[:, n0:n0+64] (cols >= CN are exact 0) ----
    for (int mc = 0; mc < NNODE; mc += 64) {
        float acc[4][4] = {};
        for (int k0 = 0; k0 < K; k0 += 16) {
#pragma unroll
            for (int p = 0; p < 4; ++p) {
                int m = la_m + p * 16, gm = mc + m, gk = k0 + la_k;
                As[la_k][m] = (gm < NNODE && gk < K) ? Ab[(long)gm * K + gk] : 0.0f;
            }
#pragma unroll
            for (int p = 0; p < 4; ++p) {
                int k = lb_k + p * 4, gk = k0 + k, gn = n0 + lb_n;
                Bs[k][lb_n] = (gk < K && gn < N) ? W[(long)gk * N + gn] : 0.0f;
            }
            __syncthreads();
#pragma unroll
            for (int k = 0; k < 16; ++k) {
                float4 av = *reinterpret_cast<const float4*>(&As[k][ty * 4]);
                float4 bv = *reinterpret_cast<const float4*>(&Bs[k][tx * 4]);
                float a[4] = {av.x, av.y, av.z, av.w};
                float bb[4] = {bv.x, bv.y, bv.z, bv.w};
#pragma unroll
                for (int i = 0; i < 4; ++i)
#pragma unroll
                    for (int j = 0; j < 4; ++j)
                        acc[i][j] = fmaf(a[i], bb[j], acc[i][j]);
            }
            __syncthreads();
        }
#pragma unroll
        for (int i = 0; i < 4; ++i) {
            int gm = mc + ty * 4 + i;
            if (gm < NNODE)
#pragma unroll
                for (int j = 0; j < 4; ++j)
                    tS[gm][tx * 4 + j] = acc[i][j];
        }
    }
    __syncthreads();

    // ---- phase 2: yS = relu(A @ tS + bias), one wave per row, lane = col ----
    const int wave = tid >> 6, lane = tid & 63;
    const float bi = (lane < CN) ? bias[n0 + lane] : 0.0f;
    for (int i = wave; i < NNODE; i += 4) {
        const long base = ((long)b * NNODE + i) * NSTRIDE;
        const int c0 = nbr_cnt[(b * NNODE + i) * 2 + 0];
        const int c1 = nbr_cnt[(b * NNODE + i) * 2 + 1];
        float s = 0.0f;
        for (int t = 0; t < c0; ++t)
            s = fmaf(nbr_val[base + t], tS[nbr_idx[base + t]][lane], s);
        for (int t = 0; t < c1; ++t) {
            long q = base + (NSTRIDE - 1) - t;
            s = fmaf(nbr_val[q], tS[nbr_idx[q]][lane], s);
        }
        yS[i][lane] = fmaxf(s + bi, 0.0f);
    }
    __syncthreads();

    // ---- phase 3: neighbor max-pool + writeout (y >= 0, so init 0 exact) ----
    float* ob = p_out + (long)b * NNODE * N;
    for (int i = wave; i < NNODE; i += 4) {
        const long base = ((long)b * NNODE + i) * NSTRIDE;
        const int c0 = nbr_cnt[(b * NNODE + i) * 2 + 0];
        float m = 0.0f;
        for (int t = 0; t < c0; ++t)
            m = fmaxf(m, yS[nbr_idx[base + t]][lane]);
        if (lane < CN) ob[(long)i * N + n0 + lane] = m;
    }
}

// Fused tail: t4 = p3 @ gc4_w; y4 = relu(adj @ t4 + gc4_b);
// rest = y4[1:] @ fc1_w + fc1_b; out = sigmoid([y4[0], rest] @ fin_w + fin_b)
__global__ __launch_bounds__(256)
void tail_kernel(const float* __restrict__ p3,      // 8512 x 75
                 const float* __restrict__ adj,
                 const float* __restrict__ gc4_w, const float* __restrict__ gc4_b,
                 const float* __restrict__ fc1_w, const float* __restrict__ fc1_b,
                 const float* __restrict__ fin_w, const float* __restrict__ fin_b,
                 float* __restrict__ out)
{
    const int b = blockIdx.x;
    const int tid = threadIdx.x;
    __shared__ float t4[NNODE];
    __shared__ float y4[NNODE];
    __shared__ float r[3];

    if (tid < NNODE) {
        const float* row = p3 + ((long)b * NNODE + tid) * 75;
        float s = 0.0f;
        for (int k = 0; k < 75; ++k) s = fmaf(row[k], gc4_w[k], s);
        t4[tid] = s;
    }
    __syncthreads();
    if (tid < NNODE) {
        const float* ar = adj + ((long)b * NNODE + tid) * NNODE;
        float s = gc4_b[0];
        for (int j = 0; j < NNODE; ++j) s = fmaf(ar[j], t4[j], s);
        y4[tid] = fmaxf(s, 0.0f);
    }
    __syncthreads();
    if (tid < 3) {
        float s = fc1_b[tid];
        for (int j = 0; j < 132; ++j) s = fmaf(y4[1 + j], fc1_w[j * 3 + tid], s);
        r[tid] = s;
    }
    __syncthreads();
    if (tid == 0) {
        float z = fin_b[0] + y4[0] * fin_w[0] + r[0] * fin_w[1]
                + r[1] * fin_w[2] + r[2] * fin_w[3];
        out[b] = 1.0f / (1.0f + expf(-z));
    }
}

extern "C" void kernel_launch(void* const* d_in, const int* in_sizes, int n_in,
                              void* d_out, int out_size, void* d_ws, size_t ws_size,
                              hipStream_t stream)
{
    const float* x     = (const float*)d_in[0];
    const float* adj   = (const float*)d_in[1];
    const float* emb_w = (const float*)d_in[2];
    const float* emb_b = (const float*)d_in[3];
    const float* gc1_w = (const float*)d_in[4];
    const float* gc1_b = (const float*)d_in[5];
    const float* gc2_w = (const float*)d_in[6];
    const float* gc2_b = (const float*)d_in[7];
    const float* gc3_w = (const float*)d_in[8];
    const float* gc3_b = (const float*)d_in[9];
    const float* gc4_w = (const float*)d_in[10];
    const float* gc4_b = (const float*)d_in[11];
    const float* fc1_w = (const float*)d_in[12];
    const float* fc1_b = (const float*)d_in[13];
    const float* fin_w = (const float*)d_in[14];
    const float* fin_b = (const float*)d_in[15];
    float* out = (float*)d_out;

    // Workspace layout (<= ~23.3 MB):
    const long MR = 64L * NNODE;                 // 8512
    float* buf0 = (float*)d_ws;                  // 8512*256 fp32
    float* buf1 = buf0 + MR * 256;               // 8512*256 fp32
    float* nbr_val = buf1 + MR * 256;            // 8512*136 fp32
    unsigned char* nbr_idx = (unsigned char*)(nbr_val + MR * NSTRIDE);
    int* nbr_cnt = (int*)(nbr_idx + MR * NSTRIDE);  // 8512*2 ints

    // 1) neighbor lists
    prep_nbr<<<dim3(NNODE, 64), 128, 0, stream>>>(adj, nbr_cnt, nbr_idx, nbr_val);
    // 2) h0 = relu(x @ emb_w + emb_b)  -> buf0 (8512 x 150)
    gemm_tiled<1, 1><<<dim3(3, 133), 256, 0, stream>>>(
        x, emb_w, emb_b, buf0, 8512, 75, 150);
    // 3) stage gc1: buf0(K=150) -> buf1 (8512 x 256)
    fused_stage<<<dim3(4, 64), 256, 0, stream>>>(
        buf0, 150, gc1_w, 256, gc1_b, nbr_cnt, nbr_idx, nbr_val, buf1);
    // 4) stage gc2: buf1(K=256) -> buf0 (8512 x 128)
    fused_stage<<<dim3(2, 64), 256, 0, stream>>>(
        buf1, 256, gc2_w, 128, gc2_b, nbr_cnt, nbr_idx, nbr_val, buf0);
    // 5) stage gc3: buf0(K=128) -> buf1 (8512 x 75)
    fused_stage<<<dim3(2, 64), 256, 0, stream>>>(
        buf0, 128, gc3_w, 75, gc3_b, nbr_cnt, nbr_idx, nbr_val, buf1);
    // 6) tail -> out
    tail_kernel<<<dim3(64), 256, 0, stream>>>(
        buf1, adj, gc4_w, gc4_b, fc1_w, fc1_b, fin_w, fin_b, out);
}

// Round 3
// 461.482 us; speedup vs baseline: 1.1423x; 1.1423x over previous
//
#include <hip/hip_runtime.h>
#include <math.h>

// ---------------------------------------------------------------------------
// One 1024-thread block per graph (B=64). Whole network in ONE kernel:
//   prep: adj[b] -> packed sparse pair lists (val,idx), front = a>1e-5 (pool+
//         spmm), back = 0<a<=1e-5 (spmm only). counts kept in LDS.
//   emb : h0 = relu(x@emb_w+emb_b)           -> global regA (ld 152)
//   gc1 : t=h0@W (LDS) -> spmm+relu (LDS) -> pool -> p1 global regB (ld 256)
//   gc2 : ... -> p2 global regA (ld 128)
//   gc3 : ... -> pool fused with gc4 dot -> t4 in LDS (no global round-trip)
//   tail: y4 = relu(A@t4+b4); rest = y4[1:]@fc1+b; out = sigmoid(...)
// GEMM mapping: c2 = tid&63 (2 cols per lane: c2, c2+64), rg = tid>>6 (16 row
// groups), rows r = rg+16u (<=9 per thread). W k-tile (32x128) staged in LDS
// (shared across all 16 waves); p read as wave-uniform broadcast float4
// (1 load : 8 FMAs). Strides padded to 4 floats so float4 stays 16B-aligned.
// ---------------------------------------------------------------------------

#define NN 133
#define NPAIR 64     // per-row pair capacity (row nnz ~ Binom(133,0.08), max<<64)
#define CW 128       // column chunk width

template<bool VEC4, bool POOL, bool FUSE_GC4>
__device__ __forceinline__ void stage(
    const float* __restrict__ p_in, int ldp, int K,
    const float* __restrict__ W, const float* __restrict__ bias, int N,
    float* __restrict__ p_out, int ldo,
    const float2* __restrict__ pb_all, const int* c0s, const int* c1s,
    float* tS, float* yS, float* t4S,
    const float* __restrict__ gc4_w, int tid)
{
    const int c2 = tid & 63;
    const int rg = tid >> 6;
    float* Ws = yS;                       // overlay: yS reused as W staging

    for (int n0 = 0; n0 < N; n0 += CW) {
        float acc0[9], acc1[9];
#pragma unroll
        for (int u = 0; u < 9; ++u) { acc0[u] = 0.f; acc1[u] = 0.f; }

        for (int k0 = 0; k0 < K; k0 += 32) {
            __syncthreads();              // protect Ws/yS readers of prev phase
            // stage W[k0:k0+32, n0:n0+128] into LDS (zero-filled OOB)
            for (int q = tid; q < 32 * CW; q += 1024) {
                int kk = q >> 7, cc = q & (CW - 1);
                int gk = k0 + kk, gn = n0 + cc;
                Ws[q] = (gk < K && gn < N) ? W[(size_t)gk * N + gn] : 0.f;
            }
            __syncthreads();
#pragma unroll 1
            for (int ks = 0; ks < 32 && k0 + ks < K; ks += 8) {
                float w0[8], w1[8];
#pragma unroll
                for (int j = 0; j < 8; ++j) {
                    w0[j] = Ws[(ks + j) * CW + c2];
                    w1[j] = Ws[(ks + j) * CW + 64 + c2];
                }
#pragma unroll
                for (int u = 0; u < 9; ++u) {
                    int r = rg + 16 * u;
                    if (r < NN) {
                        if (VEC4) {
                            const float4* pr = reinterpret_cast<const float4*>(
                                p_in + (size_t)r * ldp + k0 + ks);
                            float4 a0 = pr[0], a1 = pr[1];
                            float av[8] = {a0.x, a0.y, a0.z, a0.w,
                                           a1.x, a1.y, a1.z, a1.w};
#pragma unroll
                            for (int j = 0; j < 8; ++j) {
                                acc0[u] = fmaf(av[j], w0[j], acc0[u]);
                                acc1[u] = fmaf(av[j], w1[j], acc1[u]);
                            }
                        } else {
                            const float* pr = p_in + (size_t)r * ldp + k0 + ks;
#pragma unroll
                            for (int j = 0; j < 8; ++j) {
                                float a = (k0 + ks + j < K) ? pr[j] : 0.f;
                                acc0[u] = fmaf(a, w0[j], acc0[u]);
                                acc1[u] = fmaf(a, w1[j], acc1[u]);
                            }
                        }
                    }
                }
            }
        }
        __syncthreads();

        if (!POOL) {   // dense layer epilogue (emb): write relu(acc+bias)
#pragma unroll 1
            for (int u = 0; u < 9; ++u) {
                int r = rg + 16 * u; if (r >= NN) break;
                int g0 = n0 + c2, g1 = n0 + 64 + c2;
                if (g0 < N) p_out[(size_t)r * ldo + g0] = fmaxf(acc0[u] + bias[g0], 0.f);
                if (g1 < N) p_out[(size_t)r * ldo + g1] = fmaxf(acc1[u] + bias[g1], 0.f);
            }
            continue;                      // next chunk (pre-staging barrier guards)
        }

        // write t chunk to LDS
#pragma unroll 1
        for (int u = 0; u < 9; ++u) {
            int r = rg + 16 * u; if (r >= NN) break;
            tS[r * CW + c2] = acc0[u];
            tS[r * CW + 64 + c2] = acc1[u];
        }
        __syncthreads();

        // SpMM + bias + relu into yS (one wave per row)
        float b0 = (n0 + c2 < N) ? bias[n0 + c2] : 0.f;
        float b1 = (n0 + 64 + c2 < N) ? bias[n0 + 64 + c2] : 0.f;
#pragma unroll 1
        for (int u = 0; u < 9; ++u) {
            int i = rg + 16 * u; if (i >= NN) break;
            const float2* pb = pb_all + i * NPAIR;
            int cc0 = c0s[i], cc1 = c1s[i];
            float s0 = 0.f, s1 = 0.f;
            for (int t = 0; t < cc0; ++t) {
                float2 f = pb[t]; int j = __float_as_int(f.y);
                s0 = fmaf(f.x, tS[j * CW + c2], s0);
                s1 = fmaf(f.x, tS[j * CW + 64 + c2], s1);
            }
            for (int t = 0; t < cc1; ++t) {
                float2 f = pb[(NPAIR - 1) - t]; int j = __float_as_int(f.y);
                s0 = fmaf(f.x, tS[j * CW + c2], s0);
                s1 = fmaf(f.x, tS[j * CW + 64 + c2], s1);
            }
            yS[i * CW + c2] = fmaxf(s0 + b0, 0.f);
            yS[i * CW + 64 + c2] = fmaxf(s1 + b1, 0.f);
        }
        __syncthreads();

        // neighbor max-pool (y>=0 so init 0 exact); optionally fuse gc4 dot
        float gw0 = 0.f, gw1 = 0.f;
        if (FUSE_GC4) {
            gw0 = (n0 + c2 < N) ? gc4_w[n0 + c2] : 0.f;
            gw1 = (n0 + 64 + c2 < N) ? gc4_w[n0 + 64 + c2] : 0.f;
        }
#pragma unroll 1
        for (int u = 0; u < 9; ++u) {
            int i = rg + 16 * u; if (i >= NN) break;
            const float2* pb = pb_all + i * NPAIR;
            int cc0 = c0s[i];
            float m0 = 0.f, m1 = 0.f;
            for (int t = 0; t < cc0; ++t) {
                int j = __float_as_int(pb[t].y);
                m0 = fmaxf(m0, yS[j * CW + c2]);
                m1 = fmaxf(m1, yS[j * CW + 64 + c2]);
            }
            if (FUSE_GC4) {
                float v = m0 * gw0 + m1 * gw1;   // per-lane partial of t4[i]
#pragma unroll
                for (int off = 32; off; off >>= 1) v += __shfl_xor(v, off, 64);
                if (c2 == 0) t4S[i] = v;
            } else {
                int g0 = n0 + c2, g1 = n0 + 64 + c2;
                if (g0 < N) p_out[(size_t)i * ldo + g0] = m0;
                if (g1 < N) p_out[(size_t)i * ldo + g1] = m1;
            }
        }
        // yS protected by next chunk's pre-staging barrier
    }
    __syncthreads();
}

__global__ __launch_bounds__(1024)
void gcn_mega(const float* __restrict__ x, const float* __restrict__ adj,
              const float* __restrict__ emb_w, const float* __restrict__ emb_b,
              const float* __restrict__ gc1_w, const float* __restrict__ gc1_b,
              const float* __restrict__ gc2_w, const float* __restrict__ gc2_b,
              const float* __restrict__ gc3_w, const float* __restrict__ gc3_b,
              const float* __restrict__ gc4_w, const float* __restrict__ gc4_b,
              const float* __restrict__ fc1_w, const float* __restrict__ fc1_b,
              const float* __restrict__ fin_w, const float* __restrict__ fin_b,
              float2* __restrict__ pairs, float* __restrict__ regA,
              float* __restrict__ regB, float* __restrict__ out)
{
    __shared__ float tS[NN * CW];
    __shared__ float yS[NN * CW];
    __shared__ int   c0s[NN], c1s[NN];
    __shared__ float t4S[NN], y4S[NN];

    const int b = blockIdx.x;
    const int tid = threadIdx.x;

    // ---- prep: sparse pair lists for graph b ----
    for (int i = tid; i < NN; i += 1024) { c0s[i] = 0; c1s[i] = 0; }
    __syncthreads();
    const float* adjb = adj + (size_t)b * NN * NN;
    float2* pb_all = pairs + (size_t)b * NN * NPAIR;
    for (int q = tid; q < NN * NN; q += 1024) {
        int i = q / NN, j = q - i * NN;
        float a = adjb[q];
        if (a > 1e-5f) {
            int s = atomicAdd(&c0s[i], 1);
            if (s < NPAIR) pb_all[i * NPAIR + s] = make_float2(a, __int_as_float(j));
        } else if (a > 0.0f) {
            int s = atomicAdd(&c1s[i], 1);
            if (s < NPAIR) pb_all[i * NPAIR + (NPAIR - 1) - s] = make_float2(a, __int_as_float(j));
        }
    }
    __syncthreads();

    const float* xb = x + (size_t)b * NN * 75;
    float* h0 = regA + (size_t)b * NN * 152;   // ld 152 (pad for float4)
    float* p1 = regB + (size_t)b * NN * 256;   // ld 256
    float* p2 = regA + (size_t)b * NN * 152;   // reuse region A, ld 128

    // emb: h0 = relu(x @ emb_w + emb_b)   (x rows unaligned -> scalar path)
    stage<false, false, false>(xb, 75, 75, emb_w, emb_b, 150, h0, 152,
                               pb_all, c0s, c1s, tS, yS, t4S, nullptr, tid);
    // gc1: p1 = pool(relu(A @ (h0@gc1_w) + b))
    stage<true, true, false>(h0, 152, 150, gc1_w, gc1_b, 256, p1, 256,
                             pb_all, c0s, c1s, tS, yS, t4S, nullptr, tid);
    // gc2: p2 = pool(relu(A @ (p1@gc2_w) + b))
    stage<true, true, false>(p1, 256, 256, gc2_w, gc2_b, 128, p2, 128,
                             pb_all, c0s, c1s, tS, yS, t4S, nullptr, tid);
    // gc3 + fused gc4 dot: t4S[i] = pool(relu(A @ (p2@gc3_w) + b)) . gc4_w
    stage<true, true, true>(p2, 128, 128, gc3_w, gc3_b, 75, nullptr, 0,
                            pb_all, c0s, c1s, tS, yS, t4S, gc4_w, tid);

    // ---- tail ----
    // y4 = relu(A @ t4 + gc4_b)
    if (tid < NN) {
        const float2* pb = pb_all + tid * NPAIR;
        int cc0 = c0s[tid], cc1 = c1s[tid];
        float s = gc4_b[0];
        for (int t = 0; t < cc0; ++t) {
            float2 f = pb[t]; s = fmaf(f.x, t4S[__float_as_int(f.y)], s);
        }
        for (int t = 0; t < cc1; ++t) {
            float2 f = pb[(NPAIR - 1) - t]; s = fmaf(f.x, t4S[__float_as_int(f.y)], s);
        }
        y4S[tid] = fmaxf(s, 0.f);
    }
    __syncthreads();
    if (tid < 3) {   // rest = y4[1:133] @ fc1_w + fc1_b
        float s = fc1_b[tid];
        for (int j = 0; j < 132; ++j) s = fmaf(y4S[1 + j], fc1_w[j * 3 + tid], s);
        t4S[tid] = s;    // reuse (y4 already materialized)
    }
    __syncthreads();
    if (tid == 0) {
        float z = fin_b[0] + y4S[0] * fin_w[0] + t4S[0] * fin_w[1]
                + t4S[1] * fin_w[2] + t4S[2] * fin_w[3];
        out[b] = 1.f / (1.f + expf(-z));
    }
}

extern "C" void kernel_launch(void* const* d_in, const int* in_sizes, int n_in,
                              void* d_out, int out_size, void* d_ws, size_t ws_size,
                              hipStream_t stream)
{
    const float* x     = (const float*)d_in[0];
    const float* adj   = (const float*)d_in[1];
    const float* emb_w = (const float*)d_in[2];
    const float* emb_b = (const float*)d_in[3];
    const float* gc1_w = (const float*)d_in[4];
    const float* gc1_b = (const float*)d_in[5];
    const float* gc2_w = (const float*)d_in[6];
    const float* gc2_b = (const float*)d_in[7];
    const float* gc3_w = (const float*)d_in[8];
    const float* gc3_b = (const float*)d_in[9];
    const float* gc4_w = (const float*)d_in[10];
    const float* gc4_b = (const float*)d_in[11];
    const float* fc1_w = (const float*)d_in[12];
    const float* fc1_b = (const float*)d_in[13];
    const float* fin_w = (const float*)d_in[14];
    const float* fin_b = (const float*)d_in[15];
    float* out = (float*)d_out;

    // ws layout (~18.2 MB): pairs | regA | regB
    float2* pairs = (float2*)d_ws;                       // 64*133*64*8 B
    float*  regA  = (float*)(pairs + 64L * NN * NPAIR);  // 64*133*152*4 B
    float*  regB  = regA + 64L * NN * 152;               // 64*133*256*4 B

    gcn_mega<<<64, 1024, 0, stream>>>(
        x, adj, emb_w, emb_b, gc1_w, gc1_b, gc2_w, gc2_b, gc3_w, gc3_b,
        gc4_w, gc4_b, fc1_w, fc1_b, fin_w, fin_b, pairs, regA, regB, out);
}

// Round 5
// 346.790 us; speedup vs baseline: 1.5201x; 1.3307x over previous
//
#include <hip/hip_runtime.h>
#include <math.h>

// ---------------------------------------------------------------------------
// B=64 graphs, NN=133 nodes. 8 plain launches (graph-capture friendly):
//  K1 prep_emb : blocks<399 -> emb GEMM tiles; blocks>=399 -> sparse prep
//  K2 t1 = h0@gc1_w (532 tiles)   K3 ypool1 (256 items, 512 thr)
//  K4 t2 = p1@gc2_w (266)         K5 ypool2 (128)
//  K6 t3 = p2@gc3_w (266)         K7 ypool3 (128)
//  K8 tail (64 blocks)
// Sparse lists per row: front = a>1e-5 (spmm+pool), back = 0<a<=1e-5 (spmm
// only). GEMM: 64x64 tile, BK=16, register-prefetch pipeline (next tile's
// global loads overlap compute). Buffers: bT / bP ping-pong, h0 aliased on bP.
// ---------------------------------------------------------------------------

#define NN 133
#define NPAIR 64

// ---------------- GEMM core: one 64x64 tile, prefetch-pipelined -------------
template<int VECA, int VECB, int RELU, int BIAS>
__device__ __forceinline__ void gemm_tile_core(
    const float* __restrict__ A, int lda, int K,
    const float* __restrict__ W, int N,
    const float* __restrict__ bias,
    float* __restrict__ C, int ldc, int padN,
    int m0, int n0, float (*As)[68], float (*Bs)[68], int tid)
{
    const int la_m = tid >> 2, la_k = (tid & 3) * 4;   // A: 64 rows x 4 float4
    const int lb_k = tid >> 4, lb_n = (tid & 15) * 4;  // B: 16 k-rows x 16 f4
    const int tx = tid & 15, ty = tid >> 4;

    float pa[4], pb[4];
    // prefetch k-tile 0
    if (VECA) {
        float4 v = *reinterpret_cast<const float4*>(
            A + (size_t)(m0 + la_m) * lda + la_k);
        pa[0] = v.x; pa[1] = v.y; pa[2] = v.z; pa[3] = v.w;
    } else {
#pragma unroll
        for (int j = 0; j < 4; ++j) {
            int gk = la_k + j;
            pa[j] = (gk < K) ? A[(size_t)(m0 + la_m) * lda + gk] : 0.f;
        }
    }
    if (VECB) {
        if (lb_k < K) {
            float4 v = *reinterpret_cast<const float4*>(
                W + (size_t)lb_k * N + n0 + lb_n);
            pb[0] = v.x; pb[1] = v.y; pb[2] = v.z; pb[3] = v.w;
        } else { pb[0] = pb[1] = pb[2] = pb[3] = 0.f; }
    } else {
#pragma unroll
        for (int j = 0; j < 4; ++j) {
            int gn = n0 + lb_n + j;
            pb[j] = (lb_k < K && gn < N) ? W[(size_t)lb_k * N + gn] : 0.f;
        }
    }

    float acc[4][4] = {};
    for (int k0 = 0; k0 < K; k0 += 16) {
        __syncthreads();                       // protect prev tile's readers
#pragma unroll
        for (int j = 0; j < 4; ++j) As[la_k + j][la_m] = pa[j];
        *reinterpret_cast<float4*>(&Bs[lb_k][lb_n]) =
            make_float4(pb[0], pb[1], pb[2], pb[3]);
        __syncthreads();
        const int kn = k0 + 16;
        if (kn < K) {                          // prefetch next (overlaps FMAs)
            if (VECA) {
                float4 v = *reinterpret_cast<const float4*>(
                    A + (size_t)(m0 + la_m) * lda + kn + la_k);
                pa[0] = v.x; pa[1] = v.y; pa[2] = v.z; pa[3] = v.w;
            } else {
#pragma unroll
                for (int j = 0; j < 4; ++j) {
                    int gk = kn + la_k + j;
                    pa[j] = (gk < K) ? A[(size_t)(m0 + la_m) * lda + gk] : 0.f;
                }
            }
            int gk = kn + lb_k;
            if (VECB) {
                if (gk < K) {
                    float4 v = *reinterpret_cast<const float4*>(
                        W + (size_t)gk * N + n0 + lb_n);
                    pb[0] = v.x; pb[1] = v.y; pb[2] = v.z; pb[3] = v.w;
                } else { pb[0] = pb[1] = pb[2] = pb[3] = 0.f; }
            } else {
#pragma unroll
                for (int j = 0; j < 4; ++j) {
                    int gn = n0 + lb_n + j;
                    pb[j] = (gk < K && gn < N) ? W[(size_t)gk * N + gn] : 0.f;
                }
            }
        }
#pragma unroll
        for (int k = 0; k < 16; ++k) {
            float4 av = *reinterpret_cast<const float4*>(&As[k][ty * 4]);
            float4 bv = *reinterpret_cast<const float4*>(&Bs[k][tx * 4]);
            float a[4] = {av.x, av.y, av.z, av.w};
            float b[4] = {bv.x, bv.y, bv.z, bv.w};
#pragma unroll
            for (int i = 0; i < 4; ++i)
#pragma unroll
                for (int j = 0; j < 4; ++j)
                    acc[i][j] = fmaf(a[i], b[j], acc[i][j]);
        }
    }
#pragma unroll
    for (int i = 0; i < 4; ++i) {
        int gm = m0 + ty * 4 + i;
#pragma unroll
        for (int j = 0; j < 4; ++j) {
            int gn = n0 + tx * 4 + j;
            if (gn < padN) {                   // padN>N zero-fills padding cols
                float v = 0.f;
                if (gn < N) {
                    v = acc[i][j];
                    if (BIAS) v += bias[gn];
                    if (RELU) v = fmaxf(v, 0.f);
                }
                C[(size_t)gm * ldc + gn] = v;
            }
        }
    }
}

template<int VECA, int VECB, int RELU, int BIAS>
__global__ __launch_bounds__(256)
void gemm_k(const float* __restrict__ A, int lda, int K,
            const float* __restrict__ W, int N,
            const float* __restrict__ bias,
            float* __restrict__ C, int ldc, int padN, int tiles_n)
{
    __shared__ float As[16][68];
    __shared__ float Bs[16][68];
    const int t = blockIdx.x;
    gemm_tile_core<VECA, VECB, RELU, BIAS>(
        A, lda, K, W, N, bias, C, ldc, padN,
        (t / tiles_n) * 64, (t % tiles_n) * 64, As, Bs, threadIdx.x);
}

// -------- K1: emb GEMM tiles (blocks<399) + sparse prep (blocks>=399) -------
__global__ __launch_bounds__(256)
void prep_emb_k(const float* __restrict__ x,
                const float* __restrict__ emb_w, const float* __restrict__ emb_b,
                const float* __restrict__ adj,
                float2* __restrict__ pairs, int2* __restrict__ cnts,
                float* __restrict__ h0)
{
    __shared__ float As[16][68];
    __shared__ float Bs[16][68];
    __shared__ int c0s[NN], c1s[NN];
    const int tid = threadIdx.x;
    if (blockIdx.x < 399) {
        const int t = blockIdx.x;
        gemm_tile_core<0, 0, 1, 1>(x, 75, 75, emb_w, 150, emb_b, h0, 152, 152,
                                   (t / 3) * 64, (t % 3) * 64, As, Bs, tid);
    } else {
        const int b = blockIdx.x - 399;
        for (int i = tid; i < NN; i += 256) { c0s[i] = 0; c1s[i] = 0; }
        __syncthreads();
        const float* adjb = adj + (size_t)b * NN * NN;
        float2* pbg = pairs + (size_t)b * NN * NPAIR;
        for (int q = tid; q < NN * NN; q += 256) {
            int i = q / NN, j = q - i * NN;
            float a = adjb[q];
            if (a > 1e-5f) {
                int s = atomicAdd(&c0s[i], 1);
                pbg[i * NPAIR + s] = make_float2(a, __int_as_float(j));
            } else if (a > 0.f) {
                int s = atomicAdd(&c1s[i], 1);
                pbg[i * NPAIR + (NPAIR - 1) - s] = make_float2(a, __int_as_float(j));
            }
        }
        __syncthreads();
        for (int i = tid; i < NN; i += 256)
            cnts[b * NN + i] = make_int2(c0s[i], c1s[i]);
    }
}

// -------- SpMM(+bias+relu) -> LDS -> neighbor max-pool, 512 threads ---------
__global__ __launch_bounds__(512)
void ypool_k(const float* __restrict__ t, int ld, int N,
             const float* __restrict__ bias,
             const float2* __restrict__ pairs, const int2* __restrict__ cnts,
             float* __restrict__ p_out, int ldo, int nchunk)
{
    __shared__ float yS[NN * 64];
    const int item = blockIdx.x;
    const int b = item / nchunk, ch = item - b * nchunk;
    const int lane = threadIdx.x & 63, wave = threadIdx.x >> 6;   // 8 waves
    const int c0col = ch * 64, CN = min(64, N - c0col);
    const bool ok = lane < CN;
    const int col = c0col + (ok ? lane : 0);
    const float bi = ok ? bias[col] : 0.f;
    const float2* pb_g = pairs + (size_t)b * NN * NPAIR;
    const int2*  cn_g  = cnts + b * NN;
    const float* tb = t + (size_t)b * NN * ld;

    for (int i = wave; i < NN; i += 8) {
        int2 c = cn_g[i];
        const float2* pb = pb_g + i * NPAIR;
        float s0 = 0.f, s1 = 0.f;
        int q = 0;
        for (; q + 2 <= c.x; q += 2) {   // 2 accumulators for load ILP
            float2 f0 = pb[q], f1 = pb[q + 1];
            s0 = fmaf(f0.x, tb[(size_t)__float_as_int(f0.y) * ld + col], s0);
            s1 = fmaf(f1.x, tb[(size_t)__float_as_int(f1.y) * ld + col], s1);
        }
        if (q < c.x) {
            float2 f = pb[q];
            s0 = fmaf(f.x, tb[(size_t)__float_as_int(f.y) * ld + col], s0);
        }
        for (int r = 0; r < c.y; ++r) {
            float2 f = pb[(NPAIR - 1) - r];
            s0 = fmaf(f.x, tb[(size_t)__float_as_int(f.y) * ld + col], s0);
        }
        yS[i * 64 + lane] = fmaxf(s0 + s1 + bi, 0.f);
    }
    __syncthreads();
    float* ob = p_out + (size_t)b * NN * ldo;
    for (int i = wave; i < NN; i += 8) {
        int2 c = cn_g[i];
        const float2* pb = pb_g + i * NPAIR;
        float m = 0.f;
        for (int q2 = 0; q2 < c.x; ++q2)
            m = fmaxf(m, yS[__float_as_int(pb[q2].y) * 64 + lane]);
        if (ok) ob[(size_t)i * ldo + col] = m;
    }
}

// -------- tail: gc4 -> sparse A -> fc1 -> fin -> sigmoid --------------------
__global__ __launch_bounds__(256)
void tail_k(const float* __restrict__ p3,   // ld 76, 75 valid cols
            const float2* __restrict__ pairs, const int2* __restrict__ cnts,
            const float* __restrict__ gc4_w, const float* __restrict__ gc4_b,
            const float* __restrict__ fc1_w, const float* __restrict__ fc1_b,
            const float* __restrict__ fin_w, const float* __restrict__ fin_b,
            float* __restrict__ out)
{
    const int b = blockIdx.x, tid = threadIdx.x;
    __shared__ float t4S[NN], y4S[NN], rS[3];
    if (tid < NN) {
        const float* row = p3 + ((size_t)b * NN + tid) * 76;
        float s = 0.f;
        for (int k = 0; k < 75; ++k) s = fmaf(row[k], gc4_w[k], s);
        t4S[tid] = s;
    }
    __syncthreads();
    if (tid < NN) {
        const float2* pb = pairs + ((size_t)b * NN + tid) * NPAIR;
        int2 c = cnts[b * NN + tid];
        float s = gc4_b[0];
        for (int q = 0; q < c.x; ++q) {
            float2 f = pb[q];
            s = fmaf(f.x, t4S[__float_as_int(f.y)], s);
        }
        for (int q = 0; q < c.y; ++q) {
            float2 f = pb[(NPAIR - 1) - q];
            s = fmaf(f.x, t4S[__float_as_int(f.y)], s);
        }
        y4S[tid] = fmaxf(s, 0.f);
    }
    __syncthreads();
    if (tid < 3) {
        float s = fc1_b[tid];
        for (int j = 0; j < 132; ++j)
            s = fmaf(y4S[1 + j], fc1_w[j * 3 + tid], s);
        rS[tid] = s;
    }
    __syncthreads();
    if (tid == 0) {
        float z = fin_b[0] + y4S[0] * fin_w[0] + rS[0] * fin_w[1]
                + rS[1] * fin_w[2] + rS[2] * fin_w[3];
        out[b] = 1.f / (1.f + expf(-z));
    }
}

extern "C" void kernel_launch(void* const* d_in, const int* in_sizes, int n_in,
                              void* d_out, int out_size, void* d_ws, size_t ws_size,
                              hipStream_t stream)
{
    const float* x     = (const float*)d_in[0];
    const float* adj   = (const float*)d_in[1];
    const float* emb_w = (const float*)d_in[2];
    const float* emb_b = (const float*)d_in[3];
    const float* gc1_w = (const float*)d_in[4];
    const float* gc1_b = (const float*)d_in[5];
    const float* gc2_w = (const float*)d_in[6];
    const float* gc2_b = (const float*)d_in[7];
    const float* gc3_w = (const float*)d_in[8];
    const float* gc3_b = (const float*)d_in[9];
    const float* gc4_w = (const float*)d_in[10];
    const float* gc4_b = (const float*)d_in[11];
    const float* fc1_w = (const float*)d_in[12];
    const float* fc1_b = (const float*)d_in[13];
    const float* fin_w = (const float*)d_in[14];
    const float* fin_b = (const float*)d_in[15];
    float* out = (float*)d_out;

    // ws: pairs 4.36MB | cnts 68KB | bT 8.72MB | bP 8.72MB  (~21.9MB total)
    const long MR = 64L * NN;                    // 8512
    float2* pairs = (float2*)d_ws;
    int2*   cnts  = (int2*)(pairs + MR * NPAIR);
    float*  bT    = (float*)(cnts + MR);
    float*  bP    = bT + MR * 256;
    float*  h0    = bP;                          // h0 (ld 152) aliased on bP

    // K1: emb GEMM (399 tiles) + sparse prep (64 graphs)
    prep_emb_k<<<463, 256, 0, stream>>>(x, emb_w, emb_b, adj, pairs, cnts, h0);
    // K2: t1 = h0 @ gc1_w  (8512x150x256) -> bT ld 256
    gemm_k<1, 1, 0, 0><<<532, 256, 0, stream>>>(
        h0, 152, 150, gc1_w, 256, nullptr, bT, 256, 256, 4);
    // K3: y1/p1 -> bP ld 256
    ypool_k<<<256, 512, 0, stream>>>(bT, 256, 256, gc1_b, pairs, cnts, bP, 256, 4);
    // K4: t2 = p1 @ gc2_w  (8512x256x128) -> bT ld 128
    gemm_k<1, 1, 0, 0><<<266, 256, 0, stream>>>(
        bP, 256, 256, gc2_w, 128, nullptr, bT, 128, 128, 2);
    // K5: y2/p2 -> bP ld 128
    ypool_k<<<128, 512, 0, stream>>>(bT, 128, 128, gc2_b, pairs, cnts, bP, 128, 2);
    // K6: t3 = p2 @ gc3_w  (8512x128x75) -> bT ld 76
    gemm_k<1, 0, 0, 0><<<266, 256, 0, stream>>>(
        bP, 128, 128, gc3_w, 75, nullptr, bT, 76, 75, 2);
    // K7: y3/p3 -> bP ld 76
    ypool_k<<<128, 512, 0, stream>>>(bT, 76, 75, gc3_b, pairs, cnts, bP, 76, 2);
    // K8: tail
    tail_k<<<64, 256, 0, stream>>>(bP, pairs, cnts, gc4_w, gc4_b,
                                   fc1_w, fc1_b, fin_w, fin_b, out);
}

// Round 6
// 250.965 us; speedup vs baseline: 2.1005x; 1.3818x over previous
//
#include <hip/hip_runtime.h>
#include <math.h>

// ---------------------------------------------------------------------------
// B=64 graphs, NN=133 nodes. 11 plain launches:
//  K1 prep_emb : blocks<399 -> emb GEMM tiles; blocks>=399 -> sparse prep
//  per GCN stage: gemm_k (t=p@W) ; spmm_k (y=relu(A@t+b), 1 wave per
//  (row,chunk64)) ; pool_k (p=nbr-max(y), same shape)
//  K11 tail (64 blocks)
// Sparse lists per row: front = a>1e-5 (spmm+pool), back = 0<a<=1e-5 (spmm
// only). Pool is column-independent so y goes through global/L2 -> huge grids
// (34k waves stage1) instead of R5's 256-block LDS-staged ypool (63us, 18%occ).
// Pair loop unrolled x4 with 4 accumulators -> 4 gathers in flight.
// Buffers rotate bC->bA->bB->bC; ws = 3x8.72MB + pairs 4.36MB ~= 30.6MB.
// ---------------------------------------------------------------------------

#define NN 133
#define NPAIR 64

// ---------------- GEMM core: one 64x64 tile, prefetch-pipelined -------------
template<int VECA, int VECB, int RELU, int BIAS>
__device__ __forceinline__ void gemm_tile_core(
    const float* __restrict__ A, int lda, int K,
    const float* __restrict__ W, int N,
    const float* __restrict__ bias,
    float* __restrict__ C, int ldc, int padN,
    int m0, int n0, float (*As)[68], float (*Bs)[68], int tid)
{
    const int la_m = tid >> 2, la_k = (tid & 3) * 4;   // A: 64 rows x 4 float4
    const int lb_k = tid >> 4, lb_n = (tid & 15) * 4;  // B: 16 k-rows x 16 f4
    const int tx = tid & 15, ty = tid >> 4;

    float pa[4], pb[4];
    if (VECA) {
        float4 v = *reinterpret_cast<const float4*>(
            A + (size_t)(m0 + la_m) * lda + la_k);
        pa[0] = v.x; pa[1] = v.y; pa[2] = v.z; pa[3] = v.w;
    } else {
#pragma unroll
        for (int j = 0; j < 4; ++j) {
            int gk = la_k + j;
            pa[j] = (gk < K) ? A[(size_t)(m0 + la_m) * lda + gk] : 0.f;
        }
    }
    if (VECB) {
        if (lb_k < K) {
            float4 v = *reinterpret_cast<const float4*>(
                W + (size_t)lb_k * N + n0 + lb_n);
            pb[0] = v.x; pb[1] = v.y; pb[2] = v.z; pb[3] = v.w;
        } else { pb[0] = pb[1] = pb[2] = pb[3] = 0.f; }
    } else {
#pragma unroll
        for (int j = 0; j < 4; ++j) {
            int gn = n0 + lb_n + j;
            pb[j] = (lb_k < K && gn < N) ? W[(size_t)lb_k * N + gn] : 0.f;
        }
    }

    float acc[4][4] = {};
    for (int k0 = 0; k0 < K; k0 += 16) {
        __syncthreads();
#pragma unroll
        for (int j = 0; j < 4; ++j) As[la_k + j][la_m] = pa[j];
        *reinterpret_cast<float4*>(&Bs[lb_k][lb_n]) =
            make_float4(pb[0], pb[1], pb[2], pb[3]);
        __syncthreads();
        const int kn = k0 + 16;
        if (kn < K) {
            if (VECA) {
                float4 v = *reinterpret_cast<const float4*>(
                    A + (size_t)(m0 + la_m) * lda + kn + la_k);
                pa[0] = v.x; pa[1] = v.y; pa[2] = v.z; pa[3] = v.w;
            } else {
#pragma unroll
                for (int j = 0; j < 4; ++j) {
                    int gk = kn + la_k + j;
                    pa[j] = (gk < K) ? A[(size_t)(m0 + la_m) * lda + gk] : 0.f;
                }
            }
            int gk = kn + lb_k;
            if (VECB) {
                if (gk < K) {
                    float4 v = *reinterpret_cast<const float4*>(
                        W + (size_t)gk * N + n0 + lb_n);
                    pb[0] = v.x; pb[1] = v.y; pb[2] = v.z; pb[3] = v.w;
                } else { pb[0] = pb[1] = pb[2] = pb[3] = 0.f; }
            } else {
#pragma unroll
                for (int j = 0; j < 4; ++j) {
                    int gn = n0 + lb_n + j;
                    pb[j] = (gk < K && gn < N) ? W[(size_t)gk * N + gn] : 0.f;
                }
            }
        }
#pragma unroll
        for (int k = 0; k < 16; ++k) {
            float4 av = *reinterpret_cast<const float4*>(&As[k][ty * 4]);
            float4 bv = *reinterpret_cast<const float4*>(&Bs[k][tx * 4]);
            float a[4] = {av.x, av.y, av.z, av.w};
            float b[4] = {bv.x, bv.y, bv.z, bv.w};
#pragma unroll
            for (int i = 0; i < 4; ++i)
#pragma unroll
                for (int j = 0; j < 4; ++j)
                    acc[i][j] = fmaf(a[i], b[j], acc[i][j]);
        }
    }
#pragma unroll
    for (int i = 0; i < 4; ++i) {
        int gm = m0 + ty * 4 + i;
#pragma unroll
        for (int j = 0; j < 4; ++j) {
            int gn = n0 + tx * 4 + j;
            if (gn < padN) {
                float v = 0.f;
                if (gn < N) {
                    v = acc[i][j];
                    if (BIAS) v += bias[gn];
                    if (RELU) v = fmaxf(v, 0.f);
                }
                C[(size_t)gm * ldc + gn] = v;
            }
        }
    }
}

template<int VECA, int VECB, int RELU, int BIAS>
__global__ __launch_bounds__(256)
void gemm_k(const float* __restrict__ A, int lda, int K,
            const float* __restrict__ W, int N,
            const float* __restrict__ bias,
            float* __restrict__ C, int ldc, int padN, int tiles_n)
{
    __shared__ float As[16][68];
    __shared__ float Bs[16][68];
    const int t = blockIdx.x;
    gemm_tile_core<VECA, VECB, RELU, BIAS>(
        A, lda, K, W, N, bias, C, ldc, padN,
        (t / tiles_n) * 64, (t % tiles_n) * 64, As, Bs, threadIdx.x);
}

// -------- K1: emb GEMM tiles (blocks<399) + sparse prep (blocks>=399) -------
__global__ __launch_bounds__(256)
void prep_emb_k(const float* __restrict__ x,
                const float* __restrict__ emb_w, const float* __restrict__ emb_b,
                const float* __restrict__ adj,
                float2* __restrict__ pairs, int2* __restrict__ cnts,
                float* __restrict__ h0)
{
    __shared__ float As[16][68];
    __shared__ float Bs[16][68];
    __shared__ int c0s[NN], c1s[NN];
    const int tid = threadIdx.x;
    if (blockIdx.x < 399) {
        const int t = blockIdx.x;
        gemm_tile_core<0, 0, 1, 1>(x, 75, 75, emb_w, 150, emb_b, h0, 152, 152,
                                   (t / 3) * 64, (t % 3) * 64, As, Bs, tid);
    } else {
        const int b = blockIdx.x - 399;
        for (int i = tid; i < NN; i += 256) { c0s[i] = 0; c1s[i] = 0; }
        __syncthreads();
        const float* adjb = adj + (size_t)b * NN * NN;
        float2* pbg = pairs + (size_t)b * NN * NPAIR;
        for (int q = tid; q < NN * NN; q += 256) {
            int i = q / NN, j = q - i * NN;
            float a = adjb[q];
            if (a > 1e-5f) {
                int s = atomicAdd(&c0s[i], 1);
                pbg[i * NPAIR + s] = make_float2(a, __int_as_float(j));
            } else if (a > 0.f) {
                int s = atomicAdd(&c1s[i], 1);
                pbg[i * NPAIR + (NPAIR - 1) - s] = make_float2(a, __int_as_float(j));
            }
        }
        __syncthreads();
        for (int i = tid; i < NN; i += 256)
            cnts[b * NN + i] = make_int2(c0s[i], c1s[i]);
    }
}

// -------- spmm: y[r,col] = relu(sum_j a_rj * t[j,col] + bias[col]) ----------
// One wave per (global row r, 64-col chunk). chsh = log2(nchunk).
__global__ __launch_bounds__(256)
void spmm_k(const float* __restrict__ t, int ld, int N,
            const float* __restrict__ bias,
            const float2* __restrict__ pairs, const int2* __restrict__ cnts,
            float* __restrict__ y, int chsh)
{
    const int wave = threadIdx.x >> 6, lane = threadIdx.x & 63;
    const int item = blockIdx.x * 4 + wave;
    const int r = item >> chsh, ch = item & ((1 << chsh) - 1);
    const int b = r / NN;
    const int col0 = (ch << 6) + lane;
    const int col = min(col0, N - 1);           // clamp for safe loads
    const float2* pb = pairs + (size_t)r * NPAIR;
    const int2 c = cnts[r];
    const float* tb = t + (size_t)b * NN * ld;

    float s0 = 0.f, s1 = 0.f, s2 = 0.f, s3 = 0.f;
    int q = 0;
    for (; q + 4 <= c.x; q += 4) {              // 4 gathers in flight
        float2 f0 = pb[q], f1 = pb[q + 1], f2 = pb[q + 2], f3 = pb[q + 3];
        s0 = fmaf(f0.x, tb[(size_t)__float_as_int(f0.y) * ld + col], s0);
        s1 = fmaf(f1.x, tb[(size_t)__float_as_int(f1.y) * ld + col], s1);
        s2 = fmaf(f2.x, tb[(size_t)__float_as_int(f2.y) * ld + col], s2);
        s3 = fmaf(f3.x, tb[(size_t)__float_as_int(f3.y) * ld + col], s3);
    }
    for (; q < c.x; ++q) {
        float2 f = pb[q];
        s0 = fmaf(f.x, tb[(size_t)__float_as_int(f.y) * ld + col], s0);
    }
    for (int u = 0; u < c.y; ++u) {             // tiny-weight tail (spmm only)
        float2 f = pb[(NPAIR - 1) - u];
        s0 = fmaf(f.x, tb[(size_t)__float_as_int(f.y) * ld + col], s0);
    }
    if (col0 < N) {
        float s = (s0 + s1) + (s2 + s3) + bias[col0];
        y[(size_t)r * ld + col0] = fmaxf(s, 0.f);
    }
}

// -------- pool: p[r,col] = max over front-nbrs j of y[j,col] (y>=0) ---------
__global__ __launch_bounds__(256)
void pool_k(const float* __restrict__ y, int ld, int N,
            const float2* __restrict__ pairs, const int2* __restrict__ cnts,
            float* __restrict__ p, int chsh)
{
    const int wave = threadIdx.x >> 6, lane = threadIdx.x & 63;
    const int item = blockIdx.x * 4 + wave;
    const int r = item >> chsh, ch = item & ((1 << chsh) - 1);
    const int b = r / NN;
    const int col0 = (ch << 6) + lane;
    const int col = min(col0, N - 1);
    const float2* pb = pairs + (size_t)r * NPAIR;
    const int cx = cnts[r].x;
    const float* yb = y + (size_t)b * NN * ld;

    float m0 = 0.f, m1 = 0.f, m2 = 0.f, m3 = 0.f;
    int q = 0;
    for (; q + 4 <= cx; q += 4) {
        float2 f0 = pb[q], f1 = pb[q + 1], f2 = pb[q + 2], f3 = pb[q + 3];
        m0 = fmaxf(m0, yb[(size_t)__float_as_int(f0.y) * ld + col]);
        m1 = fmaxf(m1, yb[(size_t)__float_as_int(f1.y) * ld + col]);
        m2 = fmaxf(m2, yb[(size_t)__float_as_int(f2.y) * ld + col]);
        m3 = fmaxf(m3, yb[(size_t)__float_as_int(f3.y) * ld + col]);
    }
    for (; q < cx; ++q)
        m0 = fmaxf(m0, yb[(size_t)__float_as_int(pb[q].y) * ld + col]);
    if (col0 < N)
        p[(size_t)r * ld + col0] = fmaxf(fmaxf(m0, m1), fmaxf(m2, m3));
}

// -------- tail: gc4 -> sparse A -> fc1 -> fin -> sigmoid --------------------
__global__ __launch_bounds__(256)
void tail_k(const float* __restrict__ p3,   // ld 76, 75 valid cols
            const float2* __restrict__ pairs, const int2* __restrict__ cnts,
            const float* __restrict__ gc4_w, const float* __restrict__ gc4_b,
            const float* __restrict__ fc1_w, const float* __restrict__ fc1_b,
            const float* __restrict__ fin_w, const float* __restrict__ fin_b,
            float* __restrict__ out)
{
    const int b = blockIdx.x, tid = threadIdx.x;
    __shared__ float t4S[NN], y4S[NN], rS[3];
    if (tid < NN) {
        const float* row = p3 + ((size_t)b * NN + tid) * 76;
        float s = 0.f;
        for (int k = 0; k < 75; ++k) s = fmaf(row[k], gc4_w[k], s);
        t4S[tid] = s;
    }
    __syncthreads();
    if (tid < NN) {
        const float2* pb = pairs + ((size_t)b * NN + tid) * NPAIR;
        int2 c = cnts[b * NN + tid];
        float s = gc4_b[0];
        for (int q = 0; q < c.x; ++q) {
            float2 f = pb[q];
            s = fmaf(f.x, t4S[__float_as_int(f.y)], s);
        }
        for (int q = 0; q < c.y; ++q) {
            float2 f = pb[(NPAIR - 1) - q];
            s = fmaf(f.x, t4S[__float_as_int(f.y)], s);
        }
        y4S[tid] = fmaxf(s, 0.f);
    }
    __syncthreads();
    if (tid < 3) {
        float s = fc1_b[tid];
        for (int j = 0; j < 132; ++j)
            s = fmaf(y4S[1 + j], fc1_w[j * 3 + tid], s);
        rS[tid] = s;
    }
    __syncthreads();
    if (tid == 0) {
        float z = fin_b[0] + y4S[0] * fin_w[0] + rS[0] * fin_w[1]
                + rS[1] * fin_w[2] + rS[2] * fin_w[3];
        out[b] = 1.f / (1.f + expf(-z));
    }
}

extern "C" void kernel_launch(void* const* d_in, const int* in_sizes, int n_in,
                              void* d_out, int out_size, void* d_ws, size_t ws_size,
                              hipStream_t stream)
{
    const float* x     = (const float*)d_in[0];
    const float* adj   = (const float*)d_in[1];
    const float* emb_w = (const float*)d_in[2];
    const float* emb_b = (const float*)d_in[3];
    const float* gc1_w = (const float*)d_in[4];
    const float* gc1_b = (const float*)d_in[5];
    const float* gc2_w = (const float*)d_in[6];
    const float* gc2_b = (const float*)d_in[7];
    const float* gc3_w = (const float*)d_in[8];
    const float* gc3_b = (const float*)d_in[9];
    const float* gc4_w = (const float*)d_in[10];
    const float* gc4_b = (const float*)d_in[11];
    const float* fc1_w = (const float*)d_in[12];
    const float* fc1_b = (const float*)d_in[13];
    const float* fin_w = (const float*)d_in[14];
    const float* fin_b = (const float*)d_in[15];
    float* out = (float*)d_out;

    // ws: pairs 4.36MB | cnts 68KB | bA 8.72MB | bB 8.72MB | bC 8.72MB
    const long MR = 64L * NN;                    // 8512
    float2* pairs = (float2*)d_ws;
    int2*   cnts  = (int2*)(pairs + MR * NPAIR);
    float*  bA    = (float*)(cnts + MR);
    float*  bB    = bA + MR * 256;
    float*  bC    = bB + MR * 256;

    // K1: emb GEMM (399 tiles) -> bC (h0, ld 152) + sparse prep (64 graphs)
    prep_emb_k<<<463, 256, 0, stream>>>(x, emb_w, emb_b, adj, pairs, cnts, bC);
    // stage 1 (N=256, 4 chunks): t1 -> bA ; y1 -> bB ; p1 -> bC
    gemm_k<1, 1, 0, 0><<<532, 256, 0, stream>>>(
        bC, 152, 150, gc1_w, 256, nullptr, bA, 256, 256, 4);
    spmm_k<<<8512, 256, 0, stream>>>(bA, 256, 256, gc1_b, pairs, cnts, bB, 2);
    pool_k<<<8512, 256, 0, stream>>>(bB, 256, 256, pairs, cnts, bC, 2);
    // stage 2 (N=128, 2 chunks): t2 -> bA ; y2 -> bB ; p2 -> bC
    gemm_k<1, 1, 0, 0><<<266, 256, 0, stream>>>(
        bC, 256, 256, gc2_w, 128, nullptr, bA, 128, 128, 2);
    spmm_k<<<4256, 256, 0, stream>>>(bA, 128, 128, gc2_b, pairs, cnts, bB, 1);
    pool_k<<<4256, 256, 0, stream>>>(bB, 128, 128, pairs, cnts, bC, 1);
    // stage 3 (N=75, ld 76, 2 chunks): t3 -> bA ; y3 -> bB ; p3 -> bC
    gemm_k<1, 0, 0, 0><<<266, 256, 0, stream>>>(
        bC, 128, 128, gc3_w, 75, nullptr, bA, 76, 76, 2);
    spmm_k<<<4256, 256, 0, stream>>>(bA, 76, 75, gc3_b, pairs, cnts, bB, 1);
    pool_k<<<4256, 256, 0, stream>>>(bB, 76, 75, pairs, cnts, bC, 1);
    // tail
    tail_k<<<64, 256, 0, stream>>>(bC, pairs, cnts, gc4_w, gc4_b,
                                   fc1_w, fc1_b, fin_w, fin_b, out);
}